// Round 8
// baseline (69.648 us; speedup 1.0000x reference)
//
#include <hip/hip_runtime.h>

#define KDIM    1200
#define NBITS   2400
#define BATCHN  16384
#define WPAD    20    // 19 used u64 words per packed row + 1 pad -> 160B, 16B aligned
#define NDW     38    // meaningful dwords per packed row
#define ROWS    32    // batch rows per encode block
#define NPAR    1200  // parity outputs (columns 1200..2399); cols 0..1199 are identity

// ---------- pack m rows to bits (one wave per row) ----------
__global__ __launch_bounds__(256) void pack_rows_int(const int* __restrict__ src,
                                                     unsigned long long* __restrict__ dst) {
    int gtid = blockIdx.x * blockDim.x + threadIdx.x;
    int wave = gtid >> 6;
    int lane = gtid & 63;
    if (wave >= BATCHN) return;
    const int* row = src + (size_t)wave * KDIM;
    unsigned long long* orow = dst + (size_t)wave * WPAD;
    #pragma unroll
    for (int j = 0; j < WPAD; ++j) {
        int idx = j * 64 + lane;
        int v = (idx < KDIM) ? row[idx] : 0;
        unsigned long long mask = __ballot(v != 0);
        if (lane == 0) orow[j] = mask;
    }
}

// ---------- pack G parity rows (1200..2399) to bits ----------
__global__ __launch_bounds__(256) void pack_g(const float* __restrict__ G,
                                              unsigned long long* __restrict__ gp) {
    int gtid = blockIdx.x * blockDim.x + threadIdx.x;
    int wave = gtid >> 6;            // parity row index 0..1199
    int lane = gtid & 63;
    if (wave >= NPAR) return;
    const float* row = G + (size_t)(NPAR + wave) * KDIM;
    unsigned long long* orow = gp + (size_t)wave * WPAD;
    #pragma unroll
    for (int j = 0; j < WPAD; ++j) {
        int idx = j * 64 + lane;
        float v = (idx < KDIM) ? row[idx] : 0.0f;
        unsigned long long mask = __ballot(v != 0.0f);
        if (lane == 0) orow[j] = mask;
    }
}

// ---------- encode BOTH halves, ping-pong prefetch over batch rows ----------
// grid = (5, BATCHN/ROWS); block covers 256 columns (of each half) x ROWS rows.
__global__ __launch_bounds__(256, 3) void ldpc_encode(const unsigned long long* __restrict__ mp,
                                                      const unsigned long long* __restrict__ gp,
                                                      float* __restrict__ out) {
    const int tid = threadIdx.x;
    const int n   = blockIdx.x * 256 + tid;          // column 0..1199 (both halves)
    const bool nv = (n < NPAR);

    // this lane's parity-G row, 38 meaningful dwords in VGPRs
    unsigned g[NDW];
    {
        const uint4* gr = (const uint4*)(gp + (size_t)(nv ? n : 0) * WPAD);
        #pragma unroll
        for (int j = 0; j < 9; ++j) {
            uint4 v = gr[j];
            g[4 * j]     = v.x;
            g[4 * j + 1] = v.y;
            g[4 * j + 2] = v.z;
            g[4 * j + 3] = v.w;
        }
        uint4 v9 = gr[9];
        g[36] = v9.x;
        g[37] = v9.y;
    }

    const int row0 = blockIdx.y * ROWS;              // all 4 waves share these rows
    const uint4* mr = (const uint4*)(mp + (size_t)row0 * WPAD);  // block-uniform address
    const int idw   = blockIdx.x * 8 + (tid >> 5);   // dword holding bit n of a packed row
    const int shf   = tid & 31;
    float* ob = out + (size_t)row0 * NBITS;

    auto compute_store = [&](const uint4* t, unsigned idb, float* op) {
        unsigned p = 0;
        #pragma unroll
        for (int j = 0; j < 9; ++j) {
            p ^= t[j].x & g[4 * j];
            p ^= t[j].y & g[4 * j + 1];
            p ^= t[j].z & g[4 * j + 2];
            p ^= t[j].w & g[4 * j + 3];
        }
        p ^= t[9].x & g[36];
        p ^= t[9].y & g[37];
        if (nv) {
            op[n]        = __uint_as_float(0x3f800000u | ((idb >> shf) << 31));
            op[NPAR + n] = __uint_as_float(0x3f800000u | ((unsigned)__popc(p) << 31));
        }
    };

    // ping-pong software pipeline; final prefetch overruns into gp (contiguous
    // after mp in d_ws) -> always in bounds.
    uint4 ta[10], tb[10];
    unsigned ia, ib;
    #pragma unroll
    for (int j = 0; j < 10; ++j) ta[j] = mr[j];
    ia = ((const unsigned*)mr)[idw];
    const uint4* mrp = mr + 10;

    #pragma unroll 1
    for (int i = 0; i < ROWS; i += 2) {
        #pragma unroll
        for (int j = 0; j < 10; ++j) tb[j] = mrp[j];          // row i+1
        ib = ((const unsigned*)mrp)[idw];
        compute_store(ta, ia, ob);                             // row i
        ob += NBITS;
        #pragma unroll
        for (int j = 0; j < 10; ++j) ta[j] = mrp[10 + j];      // row i+2
        ia = ((const unsigned*)(mrp + 10))[idw];
        compute_store(tb, ib, ob);                             // row i+1
        ob += NBITS;
        mrp += 20;
    }
}

// ---------- fallback (workspace too small): direct parity GEMM, no assumptions ----------
__global__ __launch_bounds__(256) void ldpc_naive(const int* __restrict__ m,
                                                  const float* __restrict__ G,
                                                  float* __restrict__ out) {
    long long idx = (long long)blockIdx.x * blockDim.x + threadIdx.x;
    if (idx >= (long long)BATCHN * NBITS) return;
    int b = (int)(idx / NBITS);
    int n = (int)(idx % NBITS);
    int acc = 0;
    const int*   mr = m + (size_t)b * KDIM;
    const float* gr = G + (size_t)n * KDIM;
    for (int k = 0; k < KDIM; ++k)
        acc ^= (mr[k] & (gr[k] != 0.0f ? 1 : 0));
    out[idx] = 1.0f - 2.0f * (float)acc;
}

extern "C" void kernel_launch(void* const* d_in, const int* in_sizes, int n_in,
                              void* d_out, int out_size, void* d_ws, size_t ws_size,
                              hipStream_t stream) {
    const int*   m = (const int*)d_in[0];    // [BATCHN, KDIM] int32 (0/1)
    const float* G = (const float*)d_in[1];  // [NBITS, KDIM]  f32   (0/1), top 1200x1200 = I
    float* out = (float*)d_out;              // [BATCHN, NBITS] f32

    const size_t need = ((size_t)BATCHN + NPAR) * WPAD * sizeof(unsigned long long); // ~2.8MB
    if (ws_size >= need) {
        unsigned long long* mp = (unsigned long long*)d_ws;
        unsigned long long* gp = mp + (size_t)BATCHN * WPAD;

        pack_g       <<<(NPAR * 64) / 256, 256, 0, stream>>>(G, gp);
        pack_rows_int<<<(BATCHN * 64) / 256, 256, 0, stream>>>(m, mp);

        dim3 grid((NPAR + 255) / 256, BATCHN / ROWS);   // (5, 512)
        ldpc_encode<<<grid, 256, 0, stream>>>(mp, gp, out);
    } else {
        long long total = (long long)BATCHN * NBITS;
        ldpc_naive<<<(int)((total + 255) / 256), 256, 0, stream>>>(m, G, out);
    }
}

// Round 9
// 67.633 us; speedup vs baseline: 1.0298x; 1.0298x over previous
//
#include <hip/hip_runtime.h>

#define KDIM    1200
#define NBITS   2400
#define BATCHN  16384
#define WPAD    20    // 19 used u64 words per packed row + 1 pad -> 160B, 16B aligned
#define NDW     38    // meaningful dwords per packed row
#define NPAR    1200  // parity outputs (columns 1200..2399); cols 0..1199 are identity
#define ROWS    32    // batch rows per encode block
#define CH      16    // rows per LDS chunk
#define CHB     (CH * 160)   // 2560 B per chunk
#define WSLICE  (CHB / 4)    // 640 B staged per wave

// ---------- pack m rows to bits (one wave per row) ----------
__global__ __launch_bounds__(256) void pack_rows_int(const int* __restrict__ src,
                                                     unsigned long long* __restrict__ dst) {
    int gtid = blockIdx.x * blockDim.x + threadIdx.x;
    int wave = gtid >> 6;
    int lane = gtid & 63;
    if (wave >= BATCHN) return;
    const int* row = src + (size_t)wave * KDIM;
    unsigned long long* orow = dst + (size_t)wave * WPAD;
    #pragma unroll
    for (int j = 0; j < WPAD; ++j) {
        int idx = j * 64 + lane;
        int v = (idx < KDIM) ? row[idx] : 0;
        unsigned long long mask = __ballot(v != 0);
        if (lane == 0) orow[j] = mask;
    }
}

// ---------- pack G parity rows (1200..2399) to bits ----------
__global__ __launch_bounds__(256) void pack_g(const float* __restrict__ G,
                                              unsigned long long* __restrict__ gp) {
    int gtid = blockIdx.x * blockDim.x + threadIdx.x;
    int wave = gtid >> 6;            // parity row index 0..1199
    int lane = gtid & 63;
    if (wave >= NPAR) return;
    const float* row = G + (size_t)(NPAR + wave) * KDIM;
    unsigned long long* orow = gp + (size_t)wave * WPAD;
    #pragma unroll
    for (int j = 0; j < WPAD; ++j) {
        int idx = j * 64 + lane;
        float v = (idx < KDIM) ? row[idx] : 0.0f;
        unsigned long long mask = __ballot(v != 0.0f);
        if (lane == 0) orow[j] = mask;
    }
}

// ---------- encode BOTH halves; m-rows staged to LDS in double-buffered chunks ----------
// grid = (5, BATCHN/ROWS); block covers 256 columns (of each half) x ROWS rows.
__global__ __launch_bounds__(256, 4) void ldpc_encode(const unsigned long long* __restrict__ mp,
                                                      const unsigned long long* __restrict__ gp,
                                                      float* __restrict__ out) {
    __shared__ uint4 lbuf[2][CHB / 16];              // 2 x 2560 B
    const int tid  = threadIdx.x;
    const int lane = tid & 63, wv = tid >> 6;
    const int n    = blockIdx.x * 256 + tid;         // column 0..1199 (both halves)
    const bool nv  = (n < NPAR);

    // this lane's parity-G row, 38 meaningful dwords in VGPRs
    unsigned g[NDW];
    {
        const uint4* gr = (const uint4*)(gp + (size_t)(nv ? n : 0) * WPAD);
        #pragma unroll
        for (int j = 0; j < 9; ++j) {
            uint4 v = gr[j];
            g[4 * j]     = v.x;
            g[4 * j + 1] = v.y;
            g[4 * j + 2] = v.z;
            g[4 * j + 3] = v.w;
        }
        uint4 v9 = gr[9];
        g[36] = v9.x;
        g[37] = v9.y;
    }

    const int row0 = blockIdx.y * ROWS;
    const int idw  = blockIdx.x * 8 + (tid >> 5);    // dword of a packed row holding bit n
    const int shf  = tid & 31;
    float* ob = out + (size_t)row0 * NBITS;

    // stage chunk c of this block's row range into LDS buffer p (wave wv: 640 B slice)
    auto stage = [&](int c, int p) {
        const char* gsrc = (const char*)mp + ((size_t)row0 + (size_t)c * CH) * 160
                         + wv * WSLICE + lane * 16;
        if (lane < WSLICE / 16)
            __builtin_amdgcn_global_load_lds(
                (const __attribute__((address_space(1))) void*)gsrc,
                (__attribute__((address_space(3))) void*)((char*)&lbuf[p][0] + wv * WSLICE),
                16, 0, 0);
    };

    stage(0, 0);
    __syncthreads();                                  // compiler drains vmcnt before barrier

    #pragma unroll 1
    for (int c = 0; c < ROWS / CH; ++c) {
        const int p = c & 1;
        if (c + 1 < ROWS / CH) stage(c + 1, p ^ 1);   // prefetch next chunk -> other buffer

        #pragma unroll 2
        for (int i = 0; i < CH; ++i) {
            const uint4* lr = &lbuf[p][i * 10];       // 160 B packed row, uniform address
            uint4 t[10];
            #pragma unroll
            for (int j = 0; j < 10; ++j) t[j] = lr[j];
            unsigned idb = ((const unsigned*)lr)[idw];

            unsigned pa = 0;
            #pragma unroll
            for (int j = 0; j < 9; ++j) {
                pa ^= t[j].x & g[4 * j];
                pa ^= t[j].y & g[4 * j + 1];
                pa ^= t[j].z & g[4 * j + 2];
                pa ^= t[j].w & g[4 * j + 3];
            }
            pa ^= t[9].x & g[36];
            pa ^= t[9].y & g[37];

            if (nv) {
                ob[n]        = __uint_as_float(0x3f800000u | ((idb >> shf) << 31));
                ob[NPAR + n] = __uint_as_float(0x3f800000u | ((unsigned)__popc(pa) << 31));
            }
            ob += NBITS;
        }
        __syncthreads();                              // next-chunk loads done; buffers safe
    }
}

// ---------- fallback (workspace too small): direct parity GEMM, no assumptions ----------
__global__ __launch_bounds__(256) void ldpc_naive(const int* __restrict__ m,
                                                  const float* __restrict__ G,
                                                  float* __restrict__ out) {
    long long idx = (long long)blockIdx.x * blockDim.x + threadIdx.x;
    if (idx >= (long long)BATCHN * NBITS) return;
    int b = (int)(idx / NBITS);
    int n = (int)(idx % NBITS);
    int acc = 0;
    const int*   mr = m + (size_t)b * KDIM;
    const float* gr = G + (size_t)n * KDIM;
    for (int k = 0; k < KDIM; ++k)
        acc ^= (mr[k] & (gr[k] != 0.0f ? 1 : 0));
    out[idx] = 1.0f - 2.0f * (float)acc;
}

extern "C" void kernel_launch(void* const* d_in, const int* in_sizes, int n_in,
                              void* d_out, int out_size, void* d_ws, size_t ws_size,
                              hipStream_t stream) {
    const int*   m = (const int*)d_in[0];    // [BATCHN, KDIM] int32 (0/1)
    const float* G = (const float*)d_in[1];  // [NBITS, KDIM]  f32   (0/1), top 1200x1200 = I
    float* out = (float*)d_out;              // [BATCHN, NBITS] f32

    const size_t need = ((size_t)BATCHN + NPAR) * WPAD * sizeof(unsigned long long); // ~2.8MB
    if (ws_size >= need) {
        unsigned long long* mp = (unsigned long long*)d_ws;
        unsigned long long* gp = mp + (size_t)BATCHN * WPAD;

        pack_g       <<<(NPAR * 64) / 256, 256, 0, stream>>>(G, gp);
        pack_rows_int<<<(BATCHN * 64) / 256, 256, 0, stream>>>(m, mp);

        dim3 grid((NPAR + 255) / 256, BATCHN / ROWS);   // (5, 512)
        ldpc_encode<<<grid, 256, 0, stream>>>(mp, gp, out);
    } else {
        long long total = (long long)BATCHN * NBITS;
        ldpc_naive<<<(int)((total + 255) / 256), 256, 0, stream>>>(m, G, out);
    }
}